// Round 5
// baseline (548.304 us; speedup 1.0000x reference)
//
#include <hip/hip_runtime.h>

#define NM 4096
#define NK 16
#define NC 64

typedef __attribute__((ext_vector_type(8))) short s8v;
typedef __attribute__((ext_vector_type(4))) float f4v;
typedef __attribute__((ext_vector_type(2))) unsigned int u2v;

// f32 -> bf16 via native __bf16 cast: backend emits v_cvt_pk_bf16_f32 (RTNE).
__device__ __forceinline__ short f2bf(float f) {
  return __builtin_bit_cast(short, (__bf16)f);
}
__device__ __forceinline__ float bf2f(unsigned short s) {
  return __builtin_bit_cast(float, ((unsigned)s) << 16);
}
__device__ __forceinline__ s8v pack8(f4v a, f4v b) {
  s8v r;
  r[0]=f2bf(a[0]); r[1]=f2bf(a[1]); r[2]=f2bf(a[2]); r[3]=f2bf(a[3]);
  r[4]=f2bf(b[0]); r[5]=f2bf(b[1]); r[6]=f2bf(b[2]); r[7]=f2bf(b[3]);
  return r;
}

#define MFMA(a,b,c) __builtin_amdgcn_mfma_f32_16x16x32_bf16((a),(b),(c),0,0,0)

#define HSTRIDE 72                 // shorts per row: 64 + pad
#define TB8 (8*HSTRIDE)            // 8-row buffer per wave: 1152 B

// ---------------- pre-kernel 1: fold Wa1 into Wq/Wk/Wp2 (fp32, exact) ------
// ws layout (floats):
//   [    0.. 4095] Wqa1 = Wa1·Wq        (row-major [i][j])
//   [ 4096.. 8191] Wak' = -Wa1·Wk
//   [ 8192..12287] Wap  = Wa1·Wp2
//   [12288..12351] bqa  = Wa1·bq
//   [12352..12415] bc   = ba1 + Wa1·(bp2-bk)
//   [12544..     ] bf16 frag-linear images of 7 matrices (precomp2), 57344 B
__global__ void precomp_kernel(const float* __restrict__ Wq, const float* __restrict__ bq,
                               const float* __restrict__ Wk, const float* __restrict__ bk,
                               const float* __restrict__ Wp2,const float* __restrict__ bp2,
                               const float* __restrict__ Wa1,const float* __restrict__ ba1,
                               float* __restrict__ ws) {
  const int gid = blockIdx.x * 256 + threadIdx.x;
  if (gid < 3*4096) {
    const int m = gid >> 12, e = gid & 4095, i = e >> 6, j = e & 63;
    const float* R = Wa1 + i*64;
    float s = 0.f;
    if (m == 0)      { for (int l = 0; l < 64; ++l) s += R[l] * Wq [l*64 + j]; }
    else if (m == 1) { for (int l = 0; l < 64; ++l) s -= R[l] * Wk [l*64 + j]; }
    else             { for (int l = 0; l < 64; ++l) s += R[l] * Wp2[l*64 + j]; }
    ws[gid] = s;
  } else if (gid < 3*4096 + 64) {
    const int i = gid - 3*4096;
    const float* R = Wa1 + i*64;
    float s = 0.f;
    for (int l = 0; l < 64; ++l) s += R[l] * bq[l];
    ws[gid] = s;
  } else if (gid < 3*4096 + 128) {
    const int i = gid - (3*4096 + 64);
    const float* R = Wa1 + i*64;
    float s = ba1[i];
    for (int l = 0; l < 64; ++l) s += R[l] * (bp2[l] - bk[l]);
    ws[gid] = s;
  }
}

// ---------------- pre-kernel 2: bf16 frag-linear weight images --------------
// mats: 0=Wak'(nat) 1=Wv(nat) 2=Wp2(sigma) 3=Wap(sigma) 4=Wa2(pi)
//       5=Wqa1(nat) 6=W2(nat).  Group g: mat=g>>9, f=(g&511)>>6, ln=g&63.
// Runs after precomp_kernel (reads wak/wap/Wqa1 from ws).
__global__ void precomp2_kernel(const float* __restrict__ Wv,
                                const float* __restrict__ Wp2,
                                const float* __restrict__ Wa2,
                                const float* __restrict__ W2,
                                float* __restrict__ ws) {
  const int g = blockIdx.x * 256 + threadIdx.x;
  if (g >= 7*512) return;
  const int mat = g >> 9, rem = g & 511;
  const int f = rem >> 6, ln = rem & 63;
  const int t = f >> 1, h = f & 1;
  const int cc = ln & 15, qq = ln >> 4;
  const int n = 16*t + cc;
  const float* W =
    (mat==0) ? ws + 4096 :
    (mat==1) ? Wv :
    (mat==2) ? Wp2 :
    (mat==3) ? ws + 8192 :
    (mat==4) ? Wa2 :
    (mat==5) ? ws :
               W2;
  short* dst = (short*)(ws + 12544) + (size_t)g * 8;
  s8v v;
  #pragma unroll
  for (int j = 0; j < 8; ++j) {
    const int kp = h*32 + qq*8 + j;
    int k;
    if (mat == 4)                  k = 16*(2*h + (j>>2)) + 4*qq + (j&3);  // pi
    else if (mat == 2 || mat == 3) k = ((kp & 3) << 4) | (kp >> 2);       // sigma
    else                           k = kp;                                 // natural
    v[j] = f2bf(W[n*64 + k]);
  }
  *(s8v*)dst = v;
}

// ---------------- main kernel ----------------------------------------------
// 8 points per wave: 4096 waves / 1024 blocks; LDS 46656 B -> 3 blocks/CU.
// waves_per_eu(3,3): min=max=3 PINS the scheduler's occupancy target.
// Round-4 lesson: (3,8) let the scheduler chase 6 waves/EU -> VGPR=84 ->
// ~900 MB/dispatch scratch spill (WRITE_SIZE 8->195 MB). With (3,3) the
// budget is 512/3 ~= 170 and the measured live set (~124) fits with slack.
__global__ __attribute__((amdgpu_flat_work_group_size(256, 256)))
           __attribute__((amdgpu_waves_per_eu(3, 3)))
void lattn_kernel(const float* __restrict__ x,  const float* __restrict__ xyz,
                  const float* __restrict__ Wp1,const float* __restrict__ bp1,
                  const float* __restrict__ Wp2,const float* __restrict__ bp2,
                  const float* __restrict__ Wv, const float* __restrict__ bv,
                  const float* __restrict__ Wa2,const float* __restrict__ ba2,
                  const float* __restrict__ W2, const float* __restrict__ b2,
                  const float* __restrict__ ws,
                  float* __restrict__ out) {
  __shared__ __align__(16) short wlds[5*8*64*8];   // 40960 B
  __shared__ __align__(16) short qres[4*TB8];      // 4608 B (qa+bc, then res)
  __shared__ __align__(16) f4v  wp1t[4*17];        // 1088 B, stride 17 = no conflict
  // total 46656 B -> 3 blocks/CU

  const int tid = threadIdx.x;
  const float* bqa = ws + 12288;
  const float* bcv = ws + 12352;
  const short* wsb = (const short*)(ws + 12544);   // bf16 frag images

  // ---- stage 5 weight matrices: coalesced 16B copies (pre-permuted bf16) --
  #pragma unroll
  for (int i = 0; i < 10; ++i) {
    const int g = tid + i*256;                     // 2560 groups
    *(s8v*)&wlds[(size_t)g*8] = *(const s8v*)&wsb[(size_t)g*8];
  }
  // ---- wp1 table: [lq][i] = {Wp1 row n, bp1[n]}, n = sigma-frag feature ---
  if (tid < 64) {
    const int lqv = tid >> 4, ii = tid & 15;
    const int jj = ii & 7, h = ii >> 3;
    const int n = 16*(jj&3) + 2*lqv + (jj>>2) + 8*h;
    f4v t4;
    t4[0] = Wp1[n*3+0]; t4[1] = Wp1[n*3+1]; t4[2] = Wp1[n*3+2]; t4[3] = bp1[n];
    wp1t[lqv*17 + ii] = t4;
  }
  __syncthreads();

  const int w    = tid >> 6;
  const int lane = tid & 63;
  const int c    = lane & 15;
  const int lq   = lane >> 4;

  const int gw  = blockIdx.x * 4 + w;   // 0..4095 waves
  const int gp0 = gw << 3;              // 8 points per wave
  const int b   = gp0 >> 12;
  const int m0  = gp0 & (NM - 1);

  short* qbuf = qres + w * TB8;

  float bvpe[4], ba2f[4], bcf[4];
  #pragma unroll
  for (int t = 0; t < 4; ++t) {
    const int n = 16*t + c;
    bvpe[t] = bv[n] + bp2[n];
    ba2f[t] = ba2[n]; bcf[t] = bcv[n];
  }

  const long ptbase = (long)(b * NM + m0);

  // ---- group qa phase: qbuf[row p][f] = bf16(qa[p][f] + bc[f]), p<8 ------
  {
    // A rows 8..15 clamped (content only affects discarded D rows >=8)
    const float* xr = x + (ptbase + (c & 7)) * (long)(NK*NC) + 8*lq;
    s8v rA0 = pack8(*(const f4v*)xr,        *(const f4v*)(xr+4));
    s8v rA1 = pack8(*(const f4v*)(xr+32),   *(const f4v*)(xr+36));
    #pragma unroll
    for (int t = 0; t < 4; ++t) {
      s8v w0 = *(const s8v*)&wsb[(size_t)(5*512 + 2*t*64 + lane)*8];
      s8v w1 = *(const s8v*)&wsb[(size_t)(5*512 + (2*t+1)*64 + lane)*8];
      const float bb = bqa[16*t + c];
      f4v acc = {bb, bb, bb, bb};
      acc = MFMA(rA0, w0, acc);
      acc = MFMA(rA1, w1, acc);
      if (lq < 2) {
        #pragma unroll
        for (int r = 0; r < 4; ++r)
          qbuf[(4*lq + r)*HSTRIDE + 16*t + c] = f2bf(acc[r] + bcf[t]);
      }
    }
  }

  // ---- prefetch point 0 ----
  f4v nxr0, nxr1, nxr2, nxr3;
  float nza[3], nzb[3];
  {
    const float* xr = x + ptbase * (long)(NK*NC) + c*NC + 8*lq;
    nxr0 = *(const f4v*)xr;      nxr1 = *(const f4v*)(xr+4);
    nxr2 = *(const f4v*)(xr+32); nxr3 = *(const f4v*)(xr+36);
    const float* zp = xyz + ptbase * (long)(NK*3);
    nza[0] = zp[c*3+0]; nza[1] = zp[c*3+1]; nza[2] = zp[c*3+2];
    nzb[0] = zp[0];     nzb[1] = zp[1];     nzb[2] = zp[2];
  }

  // ---- main loop: 8 points ----
  #pragma unroll 1
  for (int p = 0; p < 8; ++p) {
    s8v xA0 = pack8(nxr0, nxr1);
    s8v xA1 = pack8(nxr2, nxr3);
    const float rx = nza[0] - nzb[0];
    const float ry = nza[1] - nzb[1];
    const float rz = nza[2] - nzb[2];
    if (p < 7) {
      const long prow = ptbase + p + 1;
      const float* xr = x + prow * (long)(NK*NC) + c*NC + 8*lq;
      nxr0 = *(const f4v*)xr;      nxr1 = *(const f4v*)(xr+4);
      nxr2 = *(const f4v*)(xr+32); nxr3 = *(const f4v*)(xr+36);
      const float* zp = xyz + prow * (long)(NK*3);
      nza[0] = zp[c*3+0]; nza[1] = zp[c*3+1]; nza[2] = zp[c*3+2];
      nzb[0] = zp[0];     nzb[1] = zp[1];     nzb[2] = zp[2];
    }

    // base[t][r] = qa[p][16t+4lq+r] (+bc): broadcast ds_read_b64 per t
    f4v base[4];
    #pragma unroll
    for (int t = 0; t < 4; ++t) {
      u2v q2 = *(const u2v*)&qbuf[p*HSTRIDE + 16*t + 4*lq];
      base[t][0] = __builtin_bit_cast(float, q2[0] << 16);
      base[t][1] = __builtin_bit_cast(float, q2[0] & 0xffff0000u);
      base[t][2] = __builtin_bit_cast(float, q2[1] << 16);
      base[t][3] = __builtin_bit_cast(float, q2[1] & 0xffff0000u);
    }

    // p1 = relu(Wp1·rel + bp1), per-lane in sigma fragment layout (row c)
    s8v pA0, pA1;
    #pragma unroll
    for (int i = 0; i < 8; ++i) {
      f4v w0v = wp1t[lq*17 + i];
      f4v w1v = wp1t[lq*17 + 8 + i];
      float v0 = fmaxf(fmaf(w0v[0], rx, fmaf(w0v[1], ry, fmaf(w0v[2], rz, w0v[3]))), 0.0f);
      float v1 = fmaxf(fmaf(w1v[0], rx, fmaf(w1v[1], ry, fmaf(w1v[2], rz, w1v[3]))), 0.0f);
      pA0[i] = f2bf(v0);
      pA1[i] = f2bf(v1);
    }

    // sT = (qa+bc) + Wak'·x^T + Wap·p1^T   (swapped: weights are A-operand)
    f4v s[4];
    #pragma unroll
    for (int t = 0; t < 4; ++t) {
      const short* wb = &wlds[(0*512 + 2*t*64 + lane) * 8];
      f4v acc = MFMA(*(const s8v*)wb,         xA0, base[t]);
      acc     = MFMA(*(const s8v*)(wb + 512), xA1, acc);
      s[t] = acc;
    }
    #pragma unroll
    for (int t = 0; t < 4; ++t) {
      const short* wb = &wlds[(3*512 + 2*t*64 + lane) * 8];
      f4v acc = MFMA(*(const s8v*)wb,         pA0, s[t]);
      acc     = MFMA(*(const s8v*)(wb + 512), pA1, acc);
      #pragma unroll
      for (int r = 0; r < 4; ++r) s[t][r] = fmaxf(acc[r], 0.0f);
    }
    // a1 rowfrag under pi: plain in-order pack of sT — lane-local, no LDS
    s8v aA0 = pack8(s[0], s[1]);
    s8v aA1 = pack8(s[2], s[3]);

    // logits = a1 @ Wa2^T + ba2   (mat 4, pi-stored)
    f4v lg[4];
    #pragma unroll
    for (int t = 0; t < 4; ++t) {
      const short* wb = &wlds[(4*512 + 2*t*64 + lane) * 8];
      f4v acc = {ba2f[t], ba2f[t], ba2f[t], ba2f[t]};
      acc = MFMA(aA0, *(const s8v*)wb,         acc);
      acc = MFMA(aA1, *(const s8v*)(wb + 512), acc);
      lg[t] = acc;
    }

    // vpe = x@Wv^T + p1@Wp2^T + (bv+bp2)  (overlaps softmax chains)
    f4v vpe[4];
    #pragma unroll
    for (int t = 0; t < 4; ++t) {
      const short* wb1 = &wlds[(1*512 + 2*t*64 + lane) * 8];
      const short* wb2 = &wlds[(2*512 + 2*t*64 + lane) * 8];
      f4v acc = {bvpe[t], bvpe[t], bvpe[t], bvpe[t]};
      acc = MFMA(xA0, *(const s8v*)wb1, acc);
      acc = MFMA(xA1, *(const s8v*)(wb1 + 512), acc);
      acc = MFMA(pA0, *(const s8v*)wb2, acc);
      acc = MFMA(pA1, *(const s8v*)(wb2 + 512), acc);
      vpe[t] = acc;
    }

    // softmax over 16 neighbors, per feature column; scale 1/8.
    // No max-subtraction: logits are O(1) (exp2 overflow needs |logit|>~700).
    #pragma unroll
    for (int t = 0; t < 4; ++t) {
      f4v l = lg[t];
      f4v e;
      #pragma unroll
      for (int r = 0; r < 4; ++r) e[r] = exp2f(l[r] * 0.18033688011112043f);
      float sm = (e[0] + e[1]) + (e[2] + e[3]);
      sm += __shfl_xor(sm, 16);
      sm += __shfl_xor(sm, 32);
      float pr = 0.0f;
      #pragma unroll
      for (int r = 0; r < 4; ++r) pr += e[r] * vpe[t][r];
      pr += __shfl_xor(pr, 16);
      pr += __shfl_xor(pr, 32);
      pr *= 1.0f / sm;
      if (lq == 0) qbuf[p*HSTRIDE + 16*t + c] = f2bf(pr);  // row p: qa[p] dead
    }
  }

  // ---- group final: out = res @ W2^T + b2 + raw_feature (rows < 8) -------
  {
    s8v resA0 = *(const s8v*)&qbuf[(c & 7)*HSTRIDE + 8*lq];
    s8v resA1 = *(const s8v*)&qbuf[(c & 7)*HSTRIDE + 32 + 8*lq];
    #pragma unroll
    for (int t = 0; t < 4; ++t) {
      s8v w0 = *(const s8v*)&wsb[(size_t)(6*512 + 2*t*64 + lane)*8];
      s8v w1 = *(const s8v*)&wsb[(size_t)(6*512 + (2*t+1)*64 + lane)*8];
      const float bb = b2[16*t + c];
      f4v acc = {bb, bb, bb, bb};
      acc = MFMA(resA0, w0, acc);
      acc = MFMA(resA1, w1, acc);
      if (lq < 2) {
        #pragma unroll
        for (int r = 0; r < 4; ++r) {
          const long pr2 = ptbase + 4*lq + r;
          out[pr2*NC + 16*t + c] = acc[r] + x[pr2*(long)(NK*NC) + 16*t + c];
        }
      }
    }
  }
}

extern "C" void kernel_launch(void* const* d_in, const int* in_sizes, int n_in,
                              void* d_out, int out_size, void* d_ws, size_t ws_size,
                              hipStream_t stream) {
  (void)in_sizes; (void)n_in; (void)out_size; (void)ws_size;
  const float* x   = (const float*)d_in[0];
  const float* xyz = (const float*)d_in[1];
  const float* Wq  = (const float*)d_in[2];
  const float* bq  = (const float*)d_in[3];
  const float* Wk  = (const float*)d_in[4];
  const float* bk  = (const float*)d_in[5];
  const float* Wv  = (const float*)d_in[6];
  const float* bv  = (const float*)d_in[7];
  const float* Wp1 = (const float*)d_in[8];
  const float* bp1 = (const float*)d_in[9];
  const float* Wp2 = (const float*)d_in[10];
  const float* bp2 = (const float*)d_in[11];
  const float* Wa1 = (const float*)d_in[12];
  const float* ba1 = (const float*)d_in[13];
  const float* Wa2 = (const float*)d_in[14];
  const float* ba2 = (const float*)d_in[15];
  const float* W2  = (const float*)d_in[16];
  const float* b2  = (const float*)d_in[17];
  float* out = (float*)d_out;
  float* ws  = (float*)d_ws;

  // fold Wa1 into Wq/Wk/Wp2 (12416 floats), then bf16 frag images (57344 B)
  precomp_kernel<<<dim3(49), dim3(256), 0, stream>>>(Wq, bq, Wk, bk, Wp2, bp2, Wa1, ba1, ws);
  precomp2_kernel<<<dim3(14), dim3(256), 0, stream>>>(Wv, Wp2, Wa2, W2, ws);
  // 32768 points / 8 per wave / 4 waves per block = 1024 blocks
  lattn_kernel<<<dim3(1024), dim3(256), 0, stream>>>(
      x, xyz, Wp1, bp1, Wp2, bp2, Wv, bv, Wa2, ba2, W2, b2, ws, out);
}

// Round 6
// 372.680 us; speedup vs baseline: 1.4712x; 1.4712x over previous
//
#include <hip/hip_runtime.h>

#define NM 4096
#define NK 16
#define NC 64

typedef __attribute__((ext_vector_type(8))) short s8v;
typedef __attribute__((ext_vector_type(4))) float f4v;
typedef __attribute__((ext_vector_type(2))) unsigned int u2v;

// f32 -> bf16 via native __bf16 cast: backend emits v_cvt_pk_bf16_f32 (RTNE).
__device__ __forceinline__ short f2bf(float f) {
  return __builtin_bit_cast(short, (__bf16)f);
}
__device__ __forceinline__ float bf2f(unsigned short s) {
  return __builtin_bit_cast(float, ((unsigned)s) << 16);
}
__device__ __forceinline__ s8v pack8(f4v a, f4v b) {
  s8v r;
  r[0]=f2bf(a[0]); r[1]=f2bf(a[1]); r[2]=f2bf(a[2]); r[3]=f2bf(a[3]);
  r[4]=f2bf(b[0]); r[5]=f2bf(b[1]); r[6]=f2bf(b[2]); r[7]=f2bf(b[3]);
  return r;
}

#define MFMA(a,b,c) __builtin_amdgcn_mfma_f32_16x16x32_bf16((a),(b),(c),0,0,0)

#define HSTRIDE 72                 // shorts per row: 64 + pad
#define TB8 (8*HSTRIDE)            // 8-row buffer per wave: 1152 B

// ---------------- pre-kernel 1: fold Wa1 into Wq/Wk/Wp2 (fp32, exact) ------
// ws layout (floats):
//   [    0.. 4095] Wqa1 = Wa1·Wq        (row-major [i][j])
//   [ 4096.. 8191] Wak' = -Wa1·Wk
//   [ 8192..12287] Wap  = Wa1·Wp2
//   [12288..12351] bqa  = Wa1·bq
//   [12352..12415] bc   = ba1 + Wa1·(bp2-bk)
//   [12544..     ] bf16 frag-linear images of 7 matrices (precomp2), 57344 B
__global__ void precomp_kernel(const float* __restrict__ Wq, const float* __restrict__ bq,
                               const float* __restrict__ Wk, const float* __restrict__ bk,
                               const float* __restrict__ Wp2,const float* __restrict__ bp2,
                               const float* __restrict__ Wa1,const float* __restrict__ ba1,
                               float* __restrict__ ws) {
  const int gid = blockIdx.x * 256 + threadIdx.x;
  if (gid < 3*4096) {
    const int m = gid >> 12, e = gid & 4095, i = e >> 6, j = e & 63;
    const float* R = Wa1 + i*64;
    float s = 0.f;
    if (m == 0)      { for (int l = 0; l < 64; ++l) s += R[l] * Wq [l*64 + j]; }
    else if (m == 1) { for (int l = 0; l < 64; ++l) s -= R[l] * Wk [l*64 + j]; }
    else             { for (int l = 0; l < 64; ++l) s += R[l] * Wp2[l*64 + j]; }
    ws[gid] = s;
  } else if (gid < 3*4096 + 64) {
    const int i = gid - 3*4096;
    const float* R = Wa1 + i*64;
    float s = 0.f;
    for (int l = 0; l < 64; ++l) s += R[l] * bq[l];
    ws[gid] = s;
  } else if (gid < 3*4096 + 128) {
    const int i = gid - (3*4096 + 64);
    const float* R = Wa1 + i*64;
    float s = ba1[i];
    for (int l = 0; l < 64; ++l) s += R[l] * (bp2[l] - bk[l]);
    ws[gid] = s;
  }
}

// ---------------- pre-kernel 2: bf16 frag-linear weight images --------------
// mats: 0=Wak'(nat) 1=Wv(nat) 2=Wp2(sigma) 3=Wap(sigma) 4=Wa2(pi)
//       5=Wqa1(nat) 6=W2(nat).  Group g: mat=g>>9, f=(g&511)>>6, ln=g&63.
// Runs after precomp_kernel (reads wak/wap/Wqa1 from ws).
__global__ void precomp2_kernel(const float* __restrict__ Wv,
                                const float* __restrict__ Wp2,
                                const float* __restrict__ Wa2,
                                const float* __restrict__ W2,
                                float* __restrict__ ws) {
  const int g = blockIdx.x * 256 + threadIdx.x;
  if (g >= 7*512) return;
  const int mat = g >> 9, rem = g & 511;
  const int f = rem >> 6, ln = rem & 63;
  const int t = f >> 1, h = f & 1;
  const int cc = ln & 15, qq = ln >> 4;
  const int n = 16*t + cc;
  const float* W =
    (mat==0) ? ws + 4096 :
    (mat==1) ? Wv :
    (mat==2) ? Wp2 :
    (mat==3) ? ws + 8192 :
    (mat==4) ? Wa2 :
    (mat==5) ? ws :
               W2;
  short* dst = (short*)(ws + 12544) + (size_t)g * 8;
  s8v v;
  #pragma unroll
  for (int j = 0; j < 8; ++j) {
    const int kp = h*32 + qq*8 + j;
    int k;
    if (mat == 4)                  k = 16*(2*h + (j>>2)) + 4*qq + (j&3);  // pi
    else if (mat == 2 || mat == 3) k = ((kp & 3) << 4) | (kp >> 2);       // sigma
    else                           k = kp;                                 // natural
    v[j] = f2bf(W[n*64 + k]);
  }
  *(s8v*)dst = v;
}

// ---------------- main kernel ----------------------------------------------
// 8 points per wave: 4096 waves / 1024 blocks; LDS 47168 B -> 3 blocks/CU.
// VGPR budget rule (prior session + r4/r5 measured): compiler caps arch
// VGPRs at 256/min_waves_per_eu. min=3 -> 84 (spilled ~900MB/dispatch,
// r4/r5). min=2 -> 128, and the HW occupancy tier at <=128 VGPR gives
// 4 waves/SIMD (m69) -> resident occupancy becomes LDS-capped at
// 3 blocks/CU = 12 waves/CU = 3 waves/SIMD (was 2). Live set ~115-125
// (wp1 + biases moved to LDS), so budget 128 should not spill.
__global__ __attribute__((amdgpu_flat_work_group_size(256, 256)))
           __attribute__((amdgpu_waves_per_eu(2, 2)))
void lattn_kernel(const float* __restrict__ x,  const float* __restrict__ xyz,
                  const float* __restrict__ Wp1,const float* __restrict__ bp1,
                  const float* __restrict__ Wp2,const float* __restrict__ bp2,
                  const float* __restrict__ Wv, const float* __restrict__ bv,
                  const float* __restrict__ Wa2,const float* __restrict__ ba2,
                  const float* __restrict__ W2, const float* __restrict__ b2,
                  const float* __restrict__ ws,
                  float* __restrict__ out) {
  __shared__ __align__(16) short wlds[5*8*64*8];   // 40960 B
  __shared__ __align__(16) short qres[4*TB8];      // 4608 B (qa+bc, then res)
  __shared__ __align__(16) f4v  wp1t[4*17];        // 1088 B, stride 17 = no conflict
  __shared__ float bvpet[64];                      // bv+bp2 by feature
  __shared__ float ba2t[64];                       // ba2 by feature
  // total 47168 B -> 3 blocks/CU

  const int tid = threadIdx.x;
  const float* bqa = ws + 12288;
  const float* bcv = ws + 12352;
  const short* wsb = (const short*)(ws + 12544);   // bf16 frag images

  // ---- stage 5 weight matrices: coalesced 16B copies (pre-permuted bf16) --
  #pragma unroll
  for (int i = 0; i < 10; ++i) {
    const int g = tid + i*256;                     // 2560 groups
    *(s8v*)&wlds[(size_t)g*8] = *(const s8v*)&wsb[(size_t)g*8];
  }
  // ---- wp1 table: [lq][i] = {Wp1 row n, bp1[n]}, n = sigma-frag feature ---
  if (tid < 64) {
    const int lqv = tid >> 4, ii = tid & 15;
    const int jj = ii & 7, h = ii >> 3;
    const int n = 16*(jj&3) + 2*lqv + (jj>>2) + 8*h;
    f4v t4;
    t4[0] = Wp1[n*3+0]; t4[1] = Wp1[n*3+1]; t4[2] = Wp1[n*3+2]; t4[3] = bp1[n];
    wp1t[lqv*17 + ii] = t4;
  } else if (tid < 128) {
    const int n = tid - 64;
    bvpet[n] = bv[n] + bp2[n];
  } else if (tid < 192) {
    const int n = tid - 128;
    ba2t[n] = ba2[n];
  }
  __syncthreads();

  const int w    = tid >> 6;
  const int lane = tid & 63;
  const int c    = lane & 15;
  const int lq   = lane >> 4;

  const int gw  = blockIdx.x * 4 + w;   // 0..4095 waves
  const int gp0 = gw << 3;              // 8 points per wave
  const int b   = gp0 >> 12;
  const int m0  = gp0 & (NM - 1);

  short* qbuf = qres + w * TB8;

  const long ptbase = (long)(b * NM + m0);

  // ---- group qa phase: qbuf[row p][f] = bf16(qa[p][f] + bc[f]), p<8 ------
  {
    // A rows 8..15 clamped (content only affects discarded D rows >=8)
    const float* xr = x + (ptbase + (c & 7)) * (long)(NK*NC) + 8*lq;
    s8v rA0 = pack8(*(const f4v*)xr,        *(const f4v*)(xr+4));
    s8v rA1 = pack8(*(const f4v*)(xr+32),   *(const f4v*)(xr+36));
    #pragma unroll
    for (int t = 0; t < 4; ++t) {
      s8v w0 = *(const s8v*)&wsb[(size_t)(5*512 + 2*t*64 + lane)*8];
      s8v w1 = *(const s8v*)&wsb[(size_t)(5*512 + (2*t+1)*64 + lane)*8];
      const float bb = bqa[16*t + c];
      f4v acc = {bb, bb, bb, bb};
      acc = MFMA(rA0, w0, acc);
      acc = MFMA(rA1, w1, acc);
      if (lq < 2) {
        const float bcf = bcv[16*t + c];
        #pragma unroll
        for (int r = 0; r < 4; ++r)
          qbuf[(4*lq + r)*HSTRIDE + 16*t + c] = f2bf(acc[r] + bcf);
      }
    }
  }

  // ---- prefetch point 0 ----
  f4v nxr0, nxr1, nxr2, nxr3;
  float nza[3], nzb[3];
  {
    const float* xr = x + ptbase * (long)(NK*NC) + c*NC + 8*lq;
    nxr0 = *(const f4v*)xr;      nxr1 = *(const f4v*)(xr+4);
    nxr2 = *(const f4v*)(xr+32); nxr3 = *(const f4v*)(xr+36);
    const float* zp = xyz + ptbase * (long)(NK*3);
    nza[0] = zp[c*3+0]; nza[1] = zp[c*3+1]; nza[2] = zp[c*3+2];
    nzb[0] = zp[0];     nzb[1] = zp[1];     nzb[2] = zp[2];
  }

  // ---- main loop: 8 points ----
  #pragma unroll 1
  for (int p = 0; p < 8; ++p) {
    s8v xA0 = pack8(nxr0, nxr1);
    s8v xA1 = pack8(nxr2, nxr3);
    const float rx = nza[0] - nzb[0];
    const float ry = nza[1] - nzb[1];
    const float rz = nza[2] - nzb[2];
    if (p < 7) {
      const long prow = ptbase + p + 1;
      const float* xr = x + prow * (long)(NK*NC) + c*NC + 8*lq;
      nxr0 = *(const f4v*)xr;      nxr1 = *(const f4v*)(xr+4);
      nxr2 = *(const f4v*)(xr+32); nxr3 = *(const f4v*)(xr+36);
      const float* zp = xyz + prow * (long)(NK*3);
      nza[0] = zp[c*3+0]; nza[1] = zp[c*3+1]; nza[2] = zp[c*3+2];
      nzb[0] = zp[0];     nzb[1] = zp[1];     nzb[2] = zp[2];
    }

    // base[t][r] = qa[p][16t+4lq+r] (+bc): broadcast ds_read_b64 per t
    f4v base[4];
    #pragma unroll
    for (int t = 0; t < 4; ++t) {
      u2v q2 = *(const u2v*)&qbuf[p*HSTRIDE + 16*t + 4*lq];
      base[t][0] = __builtin_bit_cast(float, q2[0] << 16);
      base[t][1] = __builtin_bit_cast(float, q2[0] & 0xffff0000u);
      base[t][2] = __builtin_bit_cast(float, q2[1] << 16);
      base[t][3] = __builtin_bit_cast(float, q2[1] & 0xffff0000u);
    }

    // p1 = relu(Wp1·rel + bp1), per-lane in sigma fragment layout (row c)
    s8v pA0, pA1;
    #pragma unroll
    for (int i = 0; i < 8; ++i) {
      f4v w0v = wp1t[lq*17 + i];
      f4v w1v = wp1t[lq*17 + 8 + i];
      float v0 = fmaxf(fmaf(w0v[0], rx, fmaf(w0v[1], ry, fmaf(w0v[2], rz, w0v[3]))), 0.0f);
      float v1 = fmaxf(fmaf(w1v[0], rx, fmaf(w1v[1], ry, fmaf(w1v[2], rz, w1v[3]))), 0.0f);
      pA0[i] = f2bf(v0);
      pA1[i] = f2bf(v1);
    }

    // sT = (qa+bc) + Wak'·x^T + Wap·p1^T   (swapped: weights are A-operand)
    f4v s[4];
    #pragma unroll
    for (int t = 0; t < 4; ++t) {
      const short* wb = &wlds[(0*512 + 2*t*64 + lane) * 8];
      f4v acc = MFMA(*(const s8v*)wb,         xA0, base[t]);
      acc     = MFMA(*(const s8v*)(wb + 512), xA1, acc);
      s[t] = acc;
    }
    #pragma unroll
    for (int t = 0; t < 4; ++t) {
      const short* wb = &wlds[(3*512 + 2*t*64 + lane) * 8];
      f4v acc = MFMA(*(const s8v*)wb,         pA0, s[t]);
      acc     = MFMA(*(const s8v*)(wb + 512), pA1, acc);
      #pragma unroll
      for (int r = 0; r < 4; ++r) s[t][r] = fmaxf(acc[r], 0.0f);
    }
    // a1 rowfrag under pi: plain in-order pack of sT — lane-local, no LDS
    s8v aA0 = pack8(s[0], s[1]);
    s8v aA1 = pack8(s[2], s[3]);

    // logits = a1 @ Wa2^T + ba2   (mat 4, pi-stored)
    f4v lg[4];
    #pragma unroll
    for (int t = 0; t < 4; ++t) {
      const short* wb = &wlds[(4*512 + 2*t*64 + lane) * 8];
      const float bb = ba2t[16*t + c];
      f4v acc = {bb, bb, bb, bb};
      acc = MFMA(aA0, *(const s8v*)wb,         acc);
      acc = MFMA(aA1, *(const s8v*)(wb + 512), acc);
      lg[t] = acc;
    }

    // vpe = x@Wv^T + p1@Wp2^T + (bv+bp2)  (overlaps softmax chains)
    f4v vpe[4];
    #pragma unroll
    for (int t = 0; t < 4; ++t) {
      const short* wb1 = &wlds[(1*512 + 2*t*64 + lane) * 8];
      const short* wb2 = &wlds[(2*512 + 2*t*64 + lane) * 8];
      const float bb = bvpet[16*t + c];
      f4v acc = {bb, bb, bb, bb};
      acc = MFMA(xA0, *(const s8v*)wb1, acc);
      acc = MFMA(xA1, *(const s8v*)(wb1 + 512), acc);
      acc = MFMA(pA0, *(const s8v*)wb2, acc);
      acc = MFMA(pA1, *(const s8v*)(wb2 + 512), acc);
      vpe[t] = acc;
    }

    // softmax over 16 neighbors, per feature column; scale 1/8.
    // No max-subtraction: logits are O(1) (exp2 overflow needs |logit|>~700).
    #pragma unroll
    for (int t = 0; t < 4; ++t) {
      f4v l = lg[t];
      f4v e;
      #pragma unroll
      for (int r = 0; r < 4; ++r) e[r] = exp2f(l[r] * 0.18033688011112043f);
      float sm = (e[0] + e[1]) + (e[2] + e[3]);
      sm += __shfl_xor(sm, 16);
      sm += __shfl_xor(sm, 32);
      float pr = 0.0f;
      #pragma unroll
      for (int r = 0; r < 4; ++r) pr += e[r] * vpe[t][r];
      pr += __shfl_xor(pr, 16);
      pr += __shfl_xor(pr, 32);
      pr *= 1.0f / sm;
      if (lq == 0) qbuf[p*HSTRIDE + 16*t + c] = f2bf(pr);  // row p: qa[p] dead
    }
  }

  // ---- group final: out = res @ W2^T + b2 + raw_feature (rows < 8) -------
  {
    s8v resA0 = *(const s8v*)&qbuf[(c & 7)*HSTRIDE + 8*lq];
    s8v resA1 = *(const s8v*)&qbuf[(c & 7)*HSTRIDE + 32 + 8*lq];
    #pragma unroll
    for (int t = 0; t < 4; ++t) {
      s8v w0 = *(const s8v*)&wsb[(size_t)(6*512 + 2*t*64 + lane)*8];
      s8v w1 = *(const s8v*)&wsb[(size_t)(6*512 + (2*t+1)*64 + lane)*8];
      const float bb = b2[16*t + c];
      f4v acc = {bb, bb, bb, bb};
      acc = MFMA(resA0, w0, acc);
      acc = MFMA(resA1, w1, acc);
      if (lq < 2) {
        #pragma unroll
        for (int r = 0; r < 4; ++r) {
          const long pr2 = ptbase + 4*lq + r;
          out[pr2*NC + 16*t + c] = acc[r] + x[pr2*(long)(NK*NC) + 16*t + c];
        }
      }
    }
  }
}

extern "C" void kernel_launch(void* const* d_in, const int* in_sizes, int n_in,
                              void* d_out, int out_size, void* d_ws, size_t ws_size,
                              hipStream_t stream) {
  (void)in_sizes; (void)n_in; (void)out_size; (void)ws_size;
  const float* x   = (const float*)d_in[0];
  const float* xyz = (const float*)d_in[1];
  const float* Wq  = (const float*)d_in[2];
  const float* bq  = (const float*)d_in[3];
  const float* Wk  = (const float*)d_in[4];
  const float* bk  = (const float*)d_in[5];
  const float* Wv  = (const float*)d_in[6];
  const float* bv  = (const float*)d_in[7];
  const float* Wp1 = (const float*)d_in[8];
  const float* bp1 = (const float*)d_in[9];
  const float* Wp2 = (const float*)d_in[10];
  const float* bp2 = (const float*)d_in[11];
  const float* Wa1 = (const float*)d_in[12];
  const float* ba1 = (const float*)d_in[13];
  const float* Wa2 = (const float*)d_in[14];
  const float* ba2 = (const float*)d_in[15];
  const float* W2  = (const float*)d_in[16];
  const float* b2  = (const float*)d_in[17];
  float* out = (float*)d_out;
  float* ws  = (float*)d_ws;

  // fold Wa1 into Wq/Wk/Wp2 (12416 floats), then bf16 frag images (57344 B)
  precomp_kernel<<<dim3(49), dim3(256), 0, stream>>>(Wq, bq, Wk, bk, Wp2, bp2, Wa1, ba1, ws);
  precomp2_kernel<<<dim3(14), dim3(256), 0, stream>>>(Wv, Wp2, Wa2, W2, ws);
  // 32768 points / 8 per wave / 4 waves per block = 1024 blocks
  lattn_kernel<<<dim3(1024), dim3(256), 0, stream>>>(
      x, xyz, Wp1, bp1, Wp2, bp2, Wv, bv, Wa2, ba2, W2, b2, ws, out);
}

// Round 7
// 372.301 us; speedup vs baseline: 1.4727x; 1.0010x over previous
//
#include <hip/hip_runtime.h>

#define NM 4096
#define NK 16
#define NC 64

typedef __attribute__((ext_vector_type(8))) short s8v;
typedef __attribute__((ext_vector_type(4))) float f4v;
typedef __attribute__((ext_vector_type(2))) unsigned int u2v;

// f32 -> bf16 via native __bf16 cast: backend emits v_cvt_pk_bf16_f32 (RTNE).
__device__ __forceinline__ short f2bf(float f) {
  return __builtin_bit_cast(short, (__bf16)f);
}
__device__ __forceinline__ float bf2f(unsigned short s) {
  return __builtin_bit_cast(float, ((unsigned)s) << 16);
}
__device__ __forceinline__ s8v pack8(f4v a, f4v b) {
  s8v r;
  r[0]=f2bf(a[0]); r[1]=f2bf(a[1]); r[2]=f2bf(a[2]); r[3]=f2bf(a[3]);
  r[4]=f2bf(b[0]); r[5]=f2bf(b[1]); r[6]=f2bf(b[2]); r[7]=f2bf(b[3]);
  return r;
}

#define MFMA(a,b,c) __builtin_amdgcn_mfma_f32_16x16x32_bf16((a),(b),(c),0,0,0)

#define HSTRIDE 72                 // shorts per row: 64 + pad
#define TB8 (8*HSTRIDE)            // 8-row buffer per wave: 1152 B

// ---------------- pre-kernel 1: fold Wa1 into Wq/Wk/Wp2 (fp32, exact) ------
// ws layout (floats):
//   [    0.. 4095] Wqa1 = Wa1·Wq        (row-major [i][j])
//   [ 4096.. 8191] Wak' = -Wa1·Wk
//   [ 8192..12287] Wap  = Wa1·Wp2
//   [12288..12351] bqa  = Wa1·bq
//   [12352..12415] bc   = ba1 + Wa1·(bp2-bk)
//   [12544..     ] bf16 frag-linear images of 7 matrices (precomp2), 57344 B
__global__ void precomp_kernel(const float* __restrict__ Wq, const float* __restrict__ bq,
                               const float* __restrict__ Wk, const float* __restrict__ bk,
                               const float* __restrict__ Wp2,const float* __restrict__ bp2,
                               const float* __restrict__ Wa1,const float* __restrict__ ba1,
                               float* __restrict__ ws) {
  const int gid = blockIdx.x * 256 + threadIdx.x;
  if (gid < 3*4096) {
    const int m = gid >> 12, e = gid & 4095, i = e >> 6, j = e & 63;
    const float* R = Wa1 + i*64;
    float s = 0.f;
    if (m == 0)      { for (int l = 0; l < 64; ++l) s += R[l] * Wq [l*64 + j]; }
    else if (m == 1) { for (int l = 0; l < 64; ++l) s -= R[l] * Wk [l*64 + j]; }
    else             { for (int l = 0; l < 64; ++l) s += R[l] * Wp2[l*64 + j]; }
    ws[gid] = s;
  } else if (gid < 3*4096 + 64) {
    const int i = gid - 3*4096;
    const float* R = Wa1 + i*64;
    float s = 0.f;
    for (int l = 0; l < 64; ++l) s += R[l] * bq[l];
    ws[gid] = s;
  } else if (gid < 3*4096 + 128) {
    const int i = gid - (3*4096 + 64);
    const float* R = Wa1 + i*64;
    float s = ba1[i];
    for (int l = 0; l < 64; ++l) s += R[l] * (bp2[l] - bk[l]);
    ws[gid] = s;
  }
}

// ---------------- pre-kernel 2: bf16 frag-linear weight images --------------
// mats: 0=Wak'(nat) 1=Wv(nat) 2=Wp2(sigma) 3=Wap(sigma) 4=Wa2(pi)
//       5=Wqa1(nat) 6=W2(nat).  Group g: mat=g>>9, f=(g&511)>>6, ln=g&63.
// Runs after precomp_kernel (reads wak/wap/Wqa1 from ws).
__global__ void precomp2_kernel(const float* __restrict__ Wv,
                                const float* __restrict__ Wp2,
                                const float* __restrict__ Wa2,
                                const float* __restrict__ W2,
                                float* __restrict__ ws) {
  const int g = blockIdx.x * 256 + threadIdx.x;
  if (g >= 7*512) return;
  const int mat = g >> 9, rem = g & 511;
  const int f = rem >> 6, ln = rem & 63;
  const int t = f >> 1, h = f & 1;
  const int cc = ln & 15, qq = ln >> 4;
  const int n = 16*t + cc;
  const float* W =
    (mat==0) ? ws + 4096 :
    (mat==1) ? Wv :
    (mat==2) ? Wp2 :
    (mat==3) ? ws + 8192 :
    (mat==4) ? Wa2 :
    (mat==5) ? ws :
               W2;
  short* dst = (short*)(ws + 12544) + (size_t)g * 8;
  s8v v;
  #pragma unroll
  for (int j = 0; j < 8; ++j) {
    const int kp = h*32 + qq*8 + j;
    int k;
    if (mat == 4)                  k = 16*(2*h + (j>>2)) + 4*qq + (j&3);  // pi
    else if (mat == 2 || mat == 3) k = ((kp & 3) << 4) | (kp >> 2);       // sigma
    else                           k = kp;                                 // natural
    v[j] = f2bf(W[n*64 + k]);
  }
  *(s8v*)dst = v;
}

// ---------------- main kernel ----------------------------------------------
// 8 points per wave: 4096 waves / 1024 blocks; LDS 47616 B -> 3 blocks/CU.
// waves_per_eu(2,2) -> VGPR budget 128 (r4/r5/r6 measured: 256/min_waves),
// and the <=128 tier allows 4 waves/SIMD (m69) so residency is LDS-capped
// at 12 waves/CU = 3 waves/SIMD.
// r6 lesson: lg[4]+vpe[4]+base[4] materialized = peak ~140 regs -> spill
// (FETCH 397MB). This version SHORTENS LIFETIMES instead: base loaded
// per-t in the s-stage, lg/vpe computed per-t inside the softmax loop.
// Peak estimate ~90-105 -> fits 128 with slack.
__global__ __attribute__((amdgpu_flat_work_group_size(256, 256)))
           __attribute__((amdgpu_waves_per_eu(2, 2)))
void lattn_kernel(const float* __restrict__ x,  const float* __restrict__ xyz,
                  const float* __restrict__ Wp1,const float* __restrict__ bp1,
                  const float* __restrict__ Wp2,const float* __restrict__ bp2,
                  const float* __restrict__ Wv, const float* __restrict__ bv,
                  const float* __restrict__ Wa2,const float* __restrict__ ba2,
                  const float* __restrict__ W2, const float* __restrict__ b2,
                  const float* __restrict__ ws,
                  float* __restrict__ out) {
  __shared__ __align__(16) short wlds[5*8*64*8];   // 40960 B
  __shared__ __align__(16) short qres[4*TB8];      // 4608 B (qa+bc, then res)
  __shared__ __align__(16) f4v  wp1t[4*17];        // 1088 B, stride 17 = no conflict
  __shared__ float bvpet[64];                      // bv+bp2 by feature
  __shared__ float ba2t[64];                       // ba2 by feature
  // total 47616 B -> 3 blocks/CU

  const int tid = threadIdx.x;
  const float* bqa = ws + 12288;
  const float* bcv = ws + 12352;
  const short* wsb = (const short*)(ws + 12544);   // bf16 frag images

  // ---- stage 5 weight matrices: coalesced 16B copies (pre-permuted bf16) --
  #pragma unroll
  for (int i = 0; i < 10; ++i) {
    const int g = tid + i*256;                     // 2560 groups
    *(s8v*)&wlds[(size_t)g*8] = *(const s8v*)&wsb[(size_t)g*8];
  }
  // ---- wp1 table: [lq][i] = {Wp1 row n, bp1[n]}, n = sigma-frag feature ---
  if (tid < 64) {
    const int lqv = tid >> 4, ii = tid & 15;
    const int jj = ii & 7, h = ii >> 3;
    const int n = 16*(jj&3) + 2*lqv + (jj>>2) + 8*h;
    f4v t4;
    t4[0] = Wp1[n*3+0]; t4[1] = Wp1[n*3+1]; t4[2] = Wp1[n*3+2]; t4[3] = bp1[n];
    wp1t[lqv*17 + ii] = t4;
  } else if (tid < 128) {
    const int n = tid - 64;
    bvpet[n] = bv[n] + bp2[n];
  } else if (tid < 192) {
    const int n = tid - 128;
    ba2t[n] = ba2[n];
  }
  __syncthreads();

  const int w    = tid >> 6;
  const int lane = tid & 63;
  const int c    = lane & 15;
  const int lq   = lane >> 4;

  const int gw  = blockIdx.x * 4 + w;   // 0..4095 waves
  const int gp0 = gw << 3;              // 8 points per wave
  const int b   = gp0 >> 12;
  const int m0  = gp0 & (NM - 1);

  short* qbuf = qres + w * TB8;

  const long ptbase = (long)(b * NM + m0);

  // ---- group qa phase: qbuf[row p][f] = bf16(qa[p][f] + bc[f]), p<8 ------
  {
    // A rows 8..15 clamped (content only affects discarded D rows >=8)
    const float* xr = x + (ptbase + (c & 7)) * (long)(NK*NC) + 8*lq;
    s8v rA0 = pack8(*(const f4v*)xr,        *(const f4v*)(xr+4));
    s8v rA1 = pack8(*(const f4v*)(xr+32),   *(const f4v*)(xr+36));
    #pragma unroll
    for (int t = 0; t < 4; ++t) {
      s8v w0 = *(const s8v*)&wsb[(size_t)(5*512 + 2*t*64 + lane)*8];
      s8v w1 = *(const s8v*)&wsb[(size_t)(5*512 + (2*t+1)*64 + lane)*8];
      const float bb = bqa[16*t + c];
      f4v acc = {bb, bb, bb, bb};
      acc = MFMA(rA0, w0, acc);
      acc = MFMA(rA1, w1, acc);
      if (lq < 2) {
        const float bcf = bcv[16*t + c];
        #pragma unroll
        for (int r = 0; r < 4; ++r)
          qbuf[(4*lq + r)*HSTRIDE + 16*t + c] = f2bf(acc[r] + bcf);
      }
    }
  }

  // ---- prefetch point 0 ----
  f4v nxr0, nxr1, nxr2, nxr3;
  float nza[3], nzb[3];
  {
    const float* xr = x + ptbase * (long)(NK*NC) + c*NC + 8*lq;
    nxr0 = *(const f4v*)xr;      nxr1 = *(const f4v*)(xr+4);
    nxr2 = *(const f4v*)(xr+32); nxr3 = *(const f4v*)(xr+36);
    const float* zp = xyz + ptbase * (long)(NK*3);
    nza[0] = zp[c*3+0]; nza[1] = zp[c*3+1]; nza[2] = zp[c*3+2];
    nzb[0] = zp[0];     nzb[1] = zp[1];     nzb[2] = zp[2];
  }

  // ---- main loop: 8 points ----
  #pragma unroll 1
  for (int p = 0; p < 8; ++p) {
    s8v xA0 = pack8(nxr0, nxr1);
    s8v xA1 = pack8(nxr2, nxr3);
    const float rx = nza[0] - nzb[0];
    const float ry = nza[1] - nzb[1];
    const float rz = nza[2] - nzb[2];
    if (p < 7) {
      const long prow = ptbase + p + 1;
      const float* xr = x + prow * (long)(NK*NC) + c*NC + 8*lq;
      nxr0 = *(const f4v*)xr;      nxr1 = *(const f4v*)(xr+4);
      nxr2 = *(const f4v*)(xr+32); nxr3 = *(const f4v*)(xr+36);
      const float* zp = xyz + prow * (long)(NK*3);
      nza[0] = zp[c*3+0]; nza[1] = zp[c*3+1]; nza[2] = zp[c*3+2];
      nzb[0] = zp[0];     nzb[1] = zp[1];     nzb[2] = zp[2];
    }

    // p1 = relu(Wp1·rel + bp1), per-lane in sigma fragment layout (row c)
    s8v pA0, pA1;
    #pragma unroll
    for (int i = 0; i < 8; ++i) {
      f4v w0v = wp1t[lq*17 + i];
      f4v w1v = wp1t[lq*17 + 8 + i];
      float v0 = fmaxf(fmaf(w0v[0], rx, fmaf(w0v[1], ry, fmaf(w0v[2], rz, w0v[3]))), 0.0f);
      float v1 = fmaxf(fmaf(w1v[0], rx, fmaf(w1v[1], ry, fmaf(w1v[2], rz, w1v[3]))), 0.0f);
      pA0[i] = f2bf(v0);
      pA1[i] = f2bf(v1);
    }

    // sT = (qa+bc) + Wak'·x^T + Wap·p1^T   (swapped: weights are A-operand)
    // base loaded per-t (ds_read_b64 broadcast), consumed immediately as C-init
    f4v s[4];
    #pragma unroll
    for (int t = 0; t < 4; ++t) {
      u2v q2 = *(const u2v*)&qbuf[p*HSTRIDE + 16*t + 4*lq];
      f4v acc;
      acc[0] = __builtin_bit_cast(float, q2[0] << 16);
      acc[1] = __builtin_bit_cast(float, q2[0] & 0xffff0000u);
      acc[2] = __builtin_bit_cast(float, q2[1] << 16);
      acc[3] = __builtin_bit_cast(float, q2[1] & 0xffff0000u);
      const short* wb = &wlds[(0*512 + 2*t*64 + lane) * 8];
      acc = MFMA(*(const s8v*)wb,         xA0, acc);
      acc = MFMA(*(const s8v*)(wb + 512), xA1, acc);
      s[t] = acc;
    }
    #pragma unroll
    for (int t = 0; t < 4; ++t) {
      const short* wb = &wlds[(3*512 + 2*t*64 + lane) * 8];
      f4v acc = MFMA(*(const s8v*)wb,         pA0, s[t]);
      acc     = MFMA(*(const s8v*)(wb + 512), pA1, acc);
      #pragma unroll
      for (int r = 0; r < 4; ++r) s[t][r] = fmaxf(acc[r], 0.0f);
    }
    // a1 rowfrag under pi: plain in-order pack of sT — lane-local, no LDS
    s8v aA0 = pack8(s[0], s[1]);
    s8v aA1 = pack8(s[2], s[3]);

    // fused per-t: logits -> softmax -> vpe -> PV reduce.
    // lg and vpe die inside each t-body (r6 spill fix: -24 peak VGPRs);
    // within a t the vpe MFMA chain is independent of the lg->exp2->shfl
    // chain, so the scheduler overlaps them.
    #pragma unroll
    for (int t = 0; t < 4; ++t) {
      const short* wb4 = &wlds[(4*512 + 2*t*64 + lane) * 8];
      const float bb2 = ba2t[16*t + c];
      f4v lgv = {bb2, bb2, bb2, bb2};
      lgv = MFMA(aA0, *(const s8v*)wb4,         lgv);
      lgv = MFMA(aA1, *(const s8v*)(wb4 + 512), lgv);

      const short* wb1 = &wlds[(1*512 + 2*t*64 + lane) * 8];
      const short* wb2 = &wlds[(2*512 + 2*t*64 + lane) * 8];
      const float bbv = bvpet[16*t + c];
      f4v vp = {bbv, bbv, bbv, bbv};
      vp = MFMA(xA0, *(const s8v*)wb1,         vp);
      vp = MFMA(xA1, *(const s8v*)(wb1 + 512), vp);
      vp = MFMA(pA0, *(const s8v*)wb2,         vp);
      vp = MFMA(pA1, *(const s8v*)(wb2 + 512), vp);

      // softmax over 16 neighbors; scale 1/8; no max-subtraction
      // (logits O(1); exp2 overflow needs |logit|>~700).
      f4v e;
      #pragma unroll
      for (int r = 0; r < 4; ++r) e[r] = exp2f(lgv[r] * 0.18033688011112043f);
      float sm = (e[0] + e[1]) + (e[2] + e[3]);
      sm += __shfl_xor(sm, 16);
      sm += __shfl_xor(sm, 32);
      float pr = 0.0f;
      #pragma unroll
      for (int r = 0; r < 4; ++r) pr += e[r] * vp[r];
      pr += __shfl_xor(pr, 16);
      pr += __shfl_xor(pr, 32);
      pr *= 1.0f / sm;
      if (lq == 0) qbuf[p*HSTRIDE + 16*t + c] = f2bf(pr);  // row p: qa[p] dead
    }
  }

  // ---- group final: out = res @ W2^T + b2 + raw_feature (rows < 8) -------
  {
    s8v resA0 = *(const s8v*)&qbuf[(c & 7)*HSTRIDE + 8*lq];
    s8v resA1 = *(const s8v*)&qbuf[(c & 7)*HSTRIDE + 32 + 8*lq];
    #pragma unroll
    for (int t = 0; t < 4; ++t) {
      s8v w0 = *(const s8v*)&wsb[(size_t)(6*512 + 2*t*64 + lane)*8];
      s8v w1 = *(const s8v*)&wsb[(size_t)(6*512 + (2*t+1)*64 + lane)*8];
      const float bb = b2[16*t + c];
      f4v acc = {bb, bb, bb, bb};
      acc = MFMA(resA0, w0, acc);
      acc = MFMA(resA1, w1, acc);
      if (lq < 2) {
        #pragma unroll
        for (int r = 0; r < 4; ++r) {
          const long pr2 = ptbase + 4*lq + r;
          out[pr2*NC + 16*t + c] = acc[r] + x[pr2*(long)(NK*NC) + 16*t + c];
        }
      }
    }
  }
}

extern "C" void kernel_launch(void* const* d_in, const int* in_sizes, int n_in,
                              void* d_out, int out_size, void* d_ws, size_t ws_size,
                              hipStream_t stream) {
  (void)in_sizes; (void)n_in; (void)out_size; (void)ws_size;
  const float* x   = (const float*)d_in[0];
  const float* xyz = (const float*)d_in[1];
  const float* Wq  = (const float*)d_in[2];
  const float* bq  = (const float*)d_in[3];
  const float* Wk  = (const float*)d_in[4];
  const float* bk  = (const float*)d_in[5];
  const float* Wv  = (const float*)d_in[6];
  const float* bv  = (const float*)d_in[7];
  const float* Wp1 = (const float*)d_in[8];
  const float* bp1 = (const float*)d_in[9];
  const float* Wp2 = (const float*)d_in[10];
  const float* bp2 = (const float*)d_in[11];
  const float* Wa1 = (const float*)d_in[12];
  const float* ba1 = (const float*)d_in[13];
  const float* Wa2 = (const float*)d_in[14];
  const float* ba2 = (const float*)d_in[15];
  const float* W2  = (const float*)d_in[16];
  const float* b2  = (const float*)d_in[17];
  float* out = (float*)d_out;
  float* ws  = (float*)d_ws;

  // fold Wa1 into Wq/Wk/Wp2 (12416 floats), then bf16 frag images (57344 B)
  precomp_kernel<<<dim3(49), dim3(256), 0, stream>>>(Wq, bq, Wk, bk, Wp2, bp2, Wa1, ba1, ws);
  precomp2_kernel<<<dim3(14), dim3(256), 0, stream>>>(Wv, Wp2, Wa2, W2, ws);
  // 32768 points / 8 per wave / 4 waves per block = 1024 blocks
  lattn_kernel<<<dim3(1024), dim3(256), 0, stream>>>(
      x, xyz, Wp1, bp1, Wp2, bp2, Wv, bv, Wa2, ba2, W2, b2, ws, out);
}

// Round 8
// 244.474 us; speedup vs baseline: 2.2428x; 1.5229x over previous
//
#include <hip/hip_runtime.h>

#define NM 4096
#define NK 16
#define NC 64

typedef __attribute__((ext_vector_type(8))) short s8v;
typedef __attribute__((ext_vector_type(4))) float f4v;
typedef __attribute__((ext_vector_type(2))) unsigned int u2v;

// f32 -> bf16 via native __bf16 cast: backend emits v_cvt_pk_bf16_f32 (RTNE).
__device__ __forceinline__ short f2bf(float f) {
  return __builtin_bit_cast(short, (__bf16)f);
}
__device__ __forceinline__ float bf2f(unsigned short s) {
  return __builtin_bit_cast(float, ((unsigned)s) << 16);
}
__device__ __forceinline__ s8v pack8(f4v a, f4v b) {
  s8v r;
  r[0]=f2bf(a[0]); r[1]=f2bf(a[1]); r[2]=f2bf(a[2]); r[3]=f2bf(a[3]);
  r[4]=f2bf(b[0]); r[5]=f2bf(b[1]); r[6]=f2bf(b[2]); r[7]=f2bf(b[3]);
  return r;
}

#define MFMA(a,b,c) __builtin_amdgcn_mfma_f32_16x16x32_bf16((a),(b),(c),0,0,0)

#define HSTRIDE 72                 // shorts per row: 64 + pad
#define TB16 (16*HSTRIDE)          // 16-row buffer per wave: 2304 B

// ---------------- pre-kernel 1: fold Wa1 into Wq/Wk/Wp2 (fp32, exact) ------
// ws layout (floats):
//   [    0.. 4095] Wqa1 = Wa1·Wq        (row-major [i][j])
//   [ 4096.. 8191] Wak' = -Wa1·Wk
//   [ 8192..12287] Wap  = Wa1·Wp2
//   [12288..12351] bqa  = Wa1·bq
//   [12352..12415] bc   = ba1 + Wa1·(bp2-bk)
//   [12544..     ] bf16 frag-linear images of 7 matrices (precomp2), 57344 B
__global__ void precomp_kernel(const float* __restrict__ Wq, const float* __restrict__ bq,
                               const float* __restrict__ Wk, const float* __restrict__ bk,
                               const float* __restrict__ Wp2,const float* __restrict__ bp2,
                               const float* __restrict__ Wa1,const float* __restrict__ ba1,
                               float* __restrict__ ws) {
  const int gid = blockIdx.x * 256 + threadIdx.x;
  if (gid < 3*4096) {
    const int m = gid >> 12, e = gid & 4095, i = e >> 6, j = e & 63;
    const float* R = Wa1 + i*64;
    float s = 0.f;
    if (m == 0)      { for (int l = 0; l < 64; ++l) s += R[l] * Wq [l*64 + j]; }
    else if (m == 1) { for (int l = 0; l < 64; ++l) s -= R[l] * Wk [l*64 + j]; }
    else             { for (int l = 0; l < 64; ++l) s += R[l] * Wp2[l*64 + j]; }
    ws[gid] = s;
  } else if (gid < 3*4096 + 64) {
    const int i = gid - 3*4096;
    const float* R = Wa1 + i*64;
    float s = 0.f;
    for (int l = 0; l < 64; ++l) s += R[l] * bq[l];
    ws[gid] = s;
  } else if (gid < 3*4096 + 128) {
    const int i = gid - (3*4096 + 64);
    const float* R = Wa1 + i*64;
    float s = ba1[i];
    for (int l = 0; l < 64; ++l) s += R[l] * (bp2[l] - bk[l]);
    ws[gid] = s;
  }
}

// ---------------- pre-kernel 2: bf16 frag-linear weight images --------------
// mats: 0=Wak'(nat) 1=Wv(nat) 2=Wp2(sigma) 3=Wap(sigma) 4=Wa2(pi)
//       5=Wqa1(nat) 6=W2(nat).  Group g: mat=g>>9, f=(g&511)>>6, ln=g&63.
// Runs after precomp_kernel (reads wak/wap/Wqa1 from ws).
__global__ void precomp2_kernel(const float* __restrict__ Wv,
                                const float* __restrict__ Wp2,
                                const float* __restrict__ Wa2,
                                const float* __restrict__ W2,
                                float* __restrict__ ws) {
  const int g = blockIdx.x * 256 + threadIdx.x;
  if (g >= 7*512) return;
  const int mat = g >> 9, rem = g & 511;
  const int f = rem >> 6, ln = rem & 63;
  const int t = f >> 1, h = f & 1;
  const int cc = ln & 15, qq = ln >> 4;
  const int n = 16*t + cc;
  const float* W =
    (mat==0) ? ws + 4096 :
    (mat==1) ? Wv :
    (mat==2) ? Wp2 :
    (mat==3) ? ws + 8192 :
    (mat==4) ? Wa2 :
    (mat==5) ? ws :
               W2;
  short* dst = (short*)(ws + 12544) + (size_t)g * 8;
  s8v v;
  #pragma unroll
  for (int j = 0; j < 8; ++j) {
    const int kp = h*32 + qq*8 + j;
    int k;
    if (mat == 4)                  k = 16*(2*h + (j>>2)) + 4*qq + (j&3);  // pi
    else if (mat == 2 || mat == 3) k = ((kp & 3) << 4) | (kp >> 2);       // sigma
    else                           k = kp;                                 // natural
    v[j] = f2bf(W[n*64 + k]);
  }
  *(s8v*)dst = v;
}

// ---------------- main kernel ----------------------------------------------
// 16 points per wave, processed as 8 PAIRS (2-point ILP): each iteration
// runs two fully independent dependency chains (r3 counters: each wave
// stalled ~79% of cycles at 2 waves/SIMD), and the pair SHARES every
// weight ds_read_b128 (half the per-point LDS traffic).
// waves_per_eu(1,8): r4-r7 measured the budget rule (256/min_waves); this
// body's demand is ~190-230 (scheduler hoists shared weight fragments), so
// any min>1 spills (r6/r7: 400-900 MB/dispatch scratch). Occupancy stays
// 2 waves/SIMD; the stall fix is intra-wave ILP, not residency.
__global__ __attribute__((amdgpu_flat_work_group_size(256, 256)))
           __attribute__((amdgpu_waves_per_eu(1, 8)))
void lattn_kernel(const float* __restrict__ x,  const float* __restrict__ xyz,
                  const float* __restrict__ Wp1,const float* __restrict__ bp1,
                  const float* __restrict__ Wp2,const float* __restrict__ bp2,
                  const float* __restrict__ Wv, const float* __restrict__ bv,
                  const float* __restrict__ Wa2,const float* __restrict__ ba2,
                  const float* __restrict__ W2, const float* __restrict__ b2,
                  const float* __restrict__ ws,
                  float* __restrict__ out) {
  __shared__ __align__(16) short wlds[5*8*64*8];   // 40960 B
  __shared__ __align__(16) short qres[4*TB16];     // 9216 B (qa+bc, then res)
  __shared__ __align__(16) f4v  wp1t[4*17];        // 1088 B, stride 17 = no conflict
  __shared__ float bvpet[64];                      // bv+bp2 by feature
  __shared__ float ba2t[64];                       // ba2 by feature
  // total 51776 B

  const int tid = threadIdx.x;
  const float* bqa = ws + 12288;
  const float* bcv = ws + 12352;
  const short* wsb = (const short*)(ws + 12544);   // bf16 frag images

  // ---- stage 5 weight matrices: coalesced 16B copies (pre-permuted bf16) --
  #pragma unroll
  for (int i = 0; i < 10; ++i) {
    const int g = tid + i*256;                     // 2560 groups
    *(s8v*)&wlds[(size_t)g*8] = *(const s8v*)&wsb[(size_t)g*8];
  }
  // ---- wp1 table: [lq][i] = {Wp1 row n, bp1[n]}, n = sigma-frag feature ---
  if (tid < 64) {
    const int lqv = tid >> 4, ii = tid & 15;
    const int jj = ii & 7, h = ii >> 3;
    const int n = 16*(jj&3) + 2*lqv + (jj>>2) + 8*h;
    f4v t4;
    t4[0] = Wp1[n*3+0]; t4[1] = Wp1[n*3+1]; t4[2] = Wp1[n*3+2]; t4[3] = bp1[n];
    wp1t[lqv*17 + ii] = t4;
  } else if (tid < 128) {
    const int n = tid - 64;
    bvpet[n] = bv[n] + bp2[n];
  } else if (tid < 192) {
    const int n = tid - 128;
    ba2t[n] = ba2[n];
  }
  __syncthreads();

  const int w    = tid >> 6;
  const int lane = tid & 63;
  const int c    = lane & 15;
  const int lq   = lane >> 4;

  const int gw  = blockIdx.x * 4 + w;   // 0..2047 waves
  const int gp0 = gw << 4;              // 16 points per wave
  const int b   = gp0 >> 12;
  const int m0  = gp0 & (NM - 1);

  short* qbuf = qres + w * TB16;

  const long ptbase = (long)(b * NM + m0);

  // ---- group qa phase: qbuf[row p][f] = bf16(qa[p][f] + bc[f]), 16 rows --
  {
    const float* xr = x + (ptbase + c) * (long)(NK*NC) + 8*lq;  // neighbor-0 row of point c
    s8v rA0 = pack8(*(const f4v*)xr,        *(const f4v*)(xr+4));
    s8v rA1 = pack8(*(const f4v*)(xr+32),   *(const f4v*)(xr+36));
    #pragma unroll
    for (int t = 0; t < 4; ++t) {
      s8v w0 = *(const s8v*)&wsb[(size_t)(5*512 + 2*t*64 + lane)*8];
      s8v w1 = *(const s8v*)&wsb[(size_t)(5*512 + (2*t+1)*64 + lane)*8];
      const float bb = bqa[16*t + c];
      f4v acc = {bb, bb, bb, bb};
      acc = MFMA(rA0, w0, acc);
      acc = MFMA(rA1, w1, acc);
      const float bcf = bcv[16*t + c];
      #pragma unroll
      for (int r = 0; r < 4; ++r)
        qbuf[(4*lq + r)*HSTRIDE + 16*t + c] = f2bf(acc[r] + bcf);
    }
  }

  // ---- prefetch pair 0 (points 0,1): raw regs, pack deferred -------------
  f4v na0, na1, na2, na3, nb0, nb1, nb2, nb3;
  float nzaa[3], nzba[3], nzab[3], nzbb[3];
  {
    const float* xra = x + ptbase * (long)(NK*NC) + c*NC + 8*lq;
    na0 = *(const f4v*)xra;      na1 = *(const f4v*)(xra+4);
    na2 = *(const f4v*)(xra+32); na3 = *(const f4v*)(xra+36);
    const float* xrb = xra + NK*NC;
    nb0 = *(const f4v*)xrb;      nb1 = *(const f4v*)(xrb+4);
    nb2 = *(const f4v*)(xrb+32); nb3 = *(const f4v*)(xrb+36);
    const float* zpa = xyz + ptbase * (long)(NK*3);
    nzaa[0]=zpa[c*3+0]; nzaa[1]=zpa[c*3+1]; nzaa[2]=zpa[c*3+2];
    nzba[0]=zpa[0];     nzba[1]=zpa[1];     nzba[2]=zpa[2];
    const float* zpb = zpa + NK*3;
    nzab[0]=zpb[c*3+0]; nzab[1]=zpb[c*3+1]; nzab[2]=zpb[c*3+2];
    nzbb[0]=zpb[0];     nzbb[1]=zpb[1];     nzbb[2]=zpb[2];
  }

  // ---- main loop: 8 pair-iterations --------------------------------------
  #pragma unroll 1
  for (int pp = 0; pp < 16; pp += 2) {
    s8v xAa0 = pack8(na0, na1), xAa1 = pack8(na2, na3);
    s8v xAb0 = pack8(nb0, nb1), xAb1 = pack8(nb2, nb3);
    const float rxa = nzaa[0]-nzba[0], rya = nzaa[1]-nzba[1], rza = nzaa[2]-nzba[2];
    const float rxb = nzab[0]-nzbb[0], ryb = nzab[1]-nzbb[1], rzb = nzab[2]-nzbb[2];
    if (pp < 14) {
      const long prow = ptbase + pp + 2;
      const float* xra = x + prow * (long)(NK*NC) + c*NC + 8*lq;
      na0 = *(const f4v*)xra;      na1 = *(const f4v*)(xra+4);
      na2 = *(const f4v*)(xra+32); na3 = *(const f4v*)(xra+36);
      const float* xrb = xra + NK*NC;
      nb0 = *(const f4v*)xrb;      nb1 = *(const f4v*)(xrb+4);
      nb2 = *(const f4v*)(xrb+32); nb3 = *(const f4v*)(xrb+36);
      const float* zpa = xyz + prow * (long)(NK*3);
      nzaa[0]=zpa[c*3+0]; nzaa[1]=zpa[c*3+1]; nzaa[2]=zpa[c*3+2];
      nzba[0]=zpa[0];     nzba[1]=zpa[1];     nzba[2]=zpa[2];
      const float* zpb = zpa + NK*3;
      nzab[0]=zpb[c*3+0]; nzab[1]=zpb[c*3+1]; nzab[2]=zpb[c*3+2];
      nzbb[0]=zpb[0];     nzbb[1]=zpb[1];     nzbb[2]=zpb[2];
    }

    // p1 for both points, per-lane sigma fragment layout (row c)
    s8v pAa0, pAa1, pAb0, pAb1;
    #pragma unroll
    for (int i = 0; i < 8; ++i) {
      f4v w0v = wp1t[lq*17 + i];
      f4v w1v = wp1t[lq*17 + 8 + i];
      float a0 = fmaxf(fmaf(w0v[0], rxa, fmaf(w0v[1], rya, fmaf(w0v[2], rza, w0v[3]))), 0.0f);
      float a1 = fmaxf(fmaf(w1v[0], rxa, fmaf(w1v[1], rya, fmaf(w1v[2], rza, w1v[3]))), 0.0f);
      float b0 = fmaxf(fmaf(w0v[0], rxb, fmaf(w0v[1], ryb, fmaf(w0v[2], rzb, w0v[3]))), 0.0f);
      float b1 = fmaxf(fmaf(w1v[0], rxb, fmaf(w1v[1], ryb, fmaf(w1v[2], rzb, w1v[3]))), 0.0f);
      pAa0[i] = f2bf(a0); pAa1[i] = f2bf(a1);
      pAb0[i] = f2bf(b0); pAb1[i] = f2bf(b1);
    }

    // sT for both points (weights shared: one ds_read pair serves a and b)
    f4v sa[4], sb[4];
    #pragma unroll
    for (int t = 0; t < 4; ++t) {
      u2v qa2 = *(const u2v*)&qbuf[pp*HSTRIDE + 16*t + 4*lq];
      u2v qb2 = *(const u2v*)&qbuf[(pp+1)*HSTRIDE + 16*t + 4*lq];
      f4v acca, accb;
      acca[0] = __builtin_bit_cast(float, qa2[0] << 16);
      acca[1] = __builtin_bit_cast(float, qa2[0] & 0xffff0000u);
      acca[2] = __builtin_bit_cast(float, qa2[1] << 16);
      acca[3] = __builtin_bit_cast(float, qa2[1] & 0xffff0000u);
      accb[0] = __builtin_bit_cast(float, qb2[0] << 16);
      accb[1] = __builtin_bit_cast(float, qb2[0] & 0xffff0000u);
      accb[2] = __builtin_bit_cast(float, qb2[1] << 16);
      accb[3] = __builtin_bit_cast(float, qb2[1] & 0xffff0000u);
      const short* wb = &wlds[(0*512 + 2*t*64 + lane) * 8];
      s8v w0 = *(const s8v*)wb;
      s8v w1 = *(const s8v*)(wb + 512);
      acca = MFMA(w0, xAa0, acca);  acca = MFMA(w1, xAa1, acca);
      accb = MFMA(w0, xAb0, accb);  accb = MFMA(w1, xAb1, accb);
      sa[t] = acca; sb[t] = accb;
    }
    #pragma unroll
    for (int t = 0; t < 4; ++t) {
      const short* wb = &wlds[(3*512 + 2*t*64 + lane) * 8];
      s8v w0 = *(const s8v*)wb;
      s8v w1 = *(const s8v*)(wb + 512);
      f4v acca = MFMA(w0, pAa0, sa[t]);  acca = MFMA(w1, pAa1, acca);
      f4v accb = MFMA(w0, pAb0, sb[t]);  accb = MFMA(w1, pAb1, accb);
      #pragma unroll
      for (int r = 0; r < 4; ++r) {
        sa[t][r] = fmaxf(acca[r], 0.0f);
        sb[t][r] = fmaxf(accb[r], 0.0f);
      }
    }
    s8v aAa0 = pack8(sa[0], sa[1]), aAa1 = pack8(sa[2], sa[3]);
    s8v aAb0 = pack8(sb[0], sb[1]), aAb1 = pack8(sb[2], sb[3]);

    // fused per-t: logits -> vpe -> softmax -> PV, both points, shared weights
    #pragma unroll
    for (int t = 0; t < 4; ++t) {
      const short* wb4 = &wlds[(4*512 + 2*t*64 + lane) * 8];
      s8v w40 = *(const s8v*)wb4;
      s8v w41 = *(const s8v*)(wb4 + 512);
      const float bb2 = ba2t[16*t + c];
      f4v lga = {bb2, bb2, bb2, bb2};
      f4v lgb = lga;
      lga = MFMA(aAa0, w40, lga);  lga = MFMA(aAa1, w41, lga);
      lgb = MFMA(aAb0, w40, lgb);  lgb = MFMA(aAb1, w41, lgb);

      const short* wb1 = &wlds[(1*512 + 2*t*64 + lane) * 8];
      const short* wb2 = &wlds[(2*512 + 2*t*64 + lane) * 8];
      s8v w10 = *(const s8v*)wb1;
      s8v w11 = *(const s8v*)(wb1 + 512);
      s8v w20 = *(const s8v*)wb2;
      s8v w21 = *(const s8v*)(wb2 + 512);
      const float bbv = bvpet[16*t + c];
      f4v vpa = {bbv, bbv, bbv, bbv};
      f4v vpb = vpa;
      vpa = MFMA(xAa0, w10, vpa);  vpa = MFMA(xAa1, w11, vpa);
      vpa = MFMA(pAa0, w20, vpa);  vpa = MFMA(pAa1, w21, vpa);
      vpb = MFMA(xAb0, w10, vpb);  vpb = MFMA(xAb1, w11, vpb);
      vpb = MFMA(pAb0, w20, vpb);  vpb = MFMA(pAb1, w21, vpb);

      // softmax over 16 neighbors; scale 1/8; no max-subtraction
      // (logits O(1); exp2 overflow needs |logit|>~700). Two independent
      // shuffle chains (a,b) interleave in the scheduler.
      f4v ea, eb;
      #pragma unroll
      for (int r = 0; r < 4; ++r) {
        ea[r] = exp2f(lga[r] * 0.18033688011112043f);
        eb[r] = exp2f(lgb[r] * 0.18033688011112043f);
      }
      float sma = (ea[0] + ea[1]) + (ea[2] + ea[3]);
      float smb = (eb[0] + eb[1]) + (eb[2] + eb[3]);
      sma += __shfl_xor(sma, 16);
      smb += __shfl_xor(smb, 16);
      sma += __shfl_xor(sma, 32);
      smb += __shfl_xor(smb, 32);
      float pra = 0.0f, prb = 0.0f;
      #pragma unroll
      for (int r = 0; r < 4; ++r) {
        pra += ea[r] * vpa[r];
        prb += eb[r] * vpb[r];
      }
      pra += __shfl_xor(pra, 16);
      prb += __shfl_xor(prb, 16);
      pra += __shfl_xor(pra, 32);
      prb += __shfl_xor(prb, 32);
      pra *= 1.0f / sma;
      prb *= 1.0f / smb;
      if (lq == 0) {
        qbuf[pp*HSTRIDE + 16*t + c]     = f2bf(pra);  // row pp: qa dead
        qbuf[(pp+1)*HSTRIDE + 16*t + c] = f2bf(prb);
      }
    }
  }

  // ---- group final: out = res @ W2^T + b2 + raw_feature (16 rows) --------
  {
    s8v resA0 = *(const s8v*)&qbuf[c*HSTRIDE + 8*lq];
    s8v resA1 = *(const s8v*)&qbuf[c*HSTRIDE + 32 + 8*lq];
    #pragma unroll
    for (int t = 0; t < 4; ++t) {
      s8v w0 = *(const s8v*)&wsb[(size_t)(6*512 + 2*t*64 + lane)*8];
      s8v w1 = *(const s8v*)&wsb[(size_t)(6*512 + (2*t+1)*64 + lane)*8];
      const float bb = b2[16*t + c];
      f4v acc = {bb, bb, bb, bb};
      acc = MFMA(resA0, w0, acc);
      acc = MFMA(resA1, w1, acc);
      #pragma unroll
      for (int r = 0; r < 4; ++r) {
        const long pr2 = ptbase + 4*lq + r;
        out[pr2*NC + 16*t + c] = acc[r] + x[pr2*(long)(NK*NC) + 16*t + c];
      }
    }
  }
}

extern "C" void kernel_launch(void* const* d_in, const int* in_sizes, int n_in,
                              void* d_out, int out_size, void* d_ws, size_t ws_size,
                              hipStream_t stream) {
  (void)in_sizes; (void)n_in; (void)out_size; (void)ws_size;
  const float* x   = (const float*)d_in[0];
  const float* xyz = (const float*)d_in[1];
  const float* Wq  = (const float*)d_in[2];
  const float* bq  = (const float*)d_in[3];
  const float* Wk  = (const float*)d_in[4];
  const float* bk  = (const float*)d_in[5];
  const float* Wv  = (const float*)d_in[6];
  const float* bv  = (const float*)d_in[7];
  const float* Wp1 = (const float*)d_in[8];
  const float* bp1 = (const float*)d_in[9];
  const float* Wp2 = (const float*)d_in[10];
  const float* bp2 = (const float*)d_in[11];
  const float* Wa1 = (const float*)d_in[12];
  const float* ba1 = (const float*)d_in[13];
  const float* Wa2 = (const float*)d_in[14];
  const float* ba2 = (const float*)d_in[15];
  const float* W2  = (const float*)d_in[16];
  const float* b2  = (const float*)d_in[17];
  float* out = (float*)d_out;
  float* ws  = (float*)d_ws;

  // fold Wa1 into Wq/Wk/Wp2 (12416 floats), then bf16 frag images (57344 B)
  precomp_kernel<<<dim3(49), dim3(256), 0, stream>>>(Wq, bq, Wk, bk, Wp2, bp2, Wa1, ba1, ws);
  precomp2_kernel<<<dim3(14), dim3(256), 0, stream>>>(Wv, Wp2, Wa2, W2, ws);
  // 32768 points / 16 per wave / 4 waves per block = 512 blocks
  lattn_kernel<<<dim3(512), dim3(256), 0, stream>>>(
      x, xyz, Wp1, bp1, Wp2, bp2, Wv, bv, Wa2, ba2, W2, b2, ws, out);
}